// Round 3
// baseline (924.346 us; speedup 1.0000x reference)
//
#include <hip/hip_runtime.h>
#include <hip/hip_bf16.h>

// ---------------- problem constants ----------------
#define BATCH   256
#define NTOK    50          // 49 patches + CLS
#define NPATCH  49
#define HID     256
#define HEADS   8
#define DH      32
#define NBLK    4
#define MLPD    1024
#define OUTD    1000
#define KPATCH  3072        // 3*32*32
#define MROWS   (BATCH*NTOK)     // 12800
#define MPATCH  (BATCH*NPATCH)   // 12544
#define MAXDEG  12               // max in-degree for t>=1 (8-neigh + self)

typedef __attribute__((ext_vector_type(4))) float  floatx4;
typedef __attribute__((ext_vector_type(8))) __bf16 bf16x8;
typedef __attribute__((ext_vector_type(4))) int    int4v;
typedef __attribute__((ext_vector_type(4))) short  short4v;

// Runtime input-dtype detection: ln1_g is all-ones. First 16-bit word is
// 0x3F80 iff the float inputs are bf16; fp32 gives 0x0000 (low mantissa).
__device__ __forceinline__ bool tag_is_bf16(const unsigned short* tag) {
    return tag[0] == 0x3F80u;
}
__device__ __forceinline__ float ldf(const void* p, long i, bool bf) {
    return bf ? __bfloat162float(((const __hip_bfloat16*)p)[i])
              : ((const float*)p)[i];
}

// fast erf-based GELU: Abramowitz-Stegun 7.1.26, |err| <= 1.5e-7 (abs).
__device__ __forceinline__ float fast_gelu(float u) {
    float s  = u * 0.70710678118654752f;
    float ax = fabsf(s);
    float t  = 1.f / (1.f + 0.3275911f * ax);
    float p  = fmaf(1.061405429f, t, -1.453152027f);
    p = fmaf(p, t, 1.421413741f);
    p = fmaf(p, t, -0.284496736f);
    p = fmaf(p, t, 0.254829592f);
    p *= t;
    float er = copysignf(1.f - p * __expf(-s * s), s);
    return 0.5f * u * (1.f + er);
}

// packed small-param layout (bf16 canonical), offsets in elements
#define OFF_BMAP 0
#define OFF_CLS  256
#define OFF_ASRC 512
#define OFF_ADST 1536
#define OFF_BGAT 2560
#define OFF_LN1G 3584
#define OFF_LN1B 4608
#define OFF_LN2G 5632
#define OFF_LN2B 6656
#define OFF_B1   7680
#define OFF_B2   11776
#define OFF_BOUT 12800
#define SP_TOTAL 13800

struct SmallSrc {
    const void *bmap, *cls, *asrc, *adst, *bgat, *ln1g, *ln1b, *ln2g, *ln2b, *b1, *b2, *bout;
};

__global__ void pack_params(SmallSrc s, const unsigned short* tag,
                            __hip_bfloat16* __restrict__ sp) {
    bool bf = tag_is_bf16(tag);
    int idx = blockIdx.x * 256 + threadIdx.x;
    if (idx >= SP_TOTAL) return;
    const void* src; long off;
    if      (idx < OFF_CLS)  { src = s.bmap; off = idx; }
    else if (idx < OFF_ASRC) { src = s.cls;  off = idx - OFF_CLS; }
    else if (idx < OFF_ADST) { src = s.asrc; off = idx - OFF_ASRC; }
    else if (idx < OFF_BGAT) { src = s.adst; off = idx - OFF_ADST; }
    else if (idx < OFF_LN1G) { src = s.bgat; off = idx - OFF_BGAT; }
    else if (idx < OFF_LN1B) { src = s.ln1g; off = idx - OFF_LN1G; }
    else if (idx < OFF_LN2G) { src = s.ln1b; off = idx - OFF_LN1B; }
    else if (idx < OFF_LN2B) { src = s.ln2g; off = idx - OFF_LN2G; }
    else if (idx < OFF_B1)   { src = s.ln2b; off = idx - OFF_LN2B; }
    else if (idx < OFF_B2)   { src = s.b1;   off = idx - OFF_B1; }
    else if (idx < OFF_BOUT) { src = s.b2;   off = idx - OFF_B2; }
    else                     { src = s.bout; off = idx - OFF_BOUT; }
    sp[idx] = __float2bfloat16(ldf(src, off, bf));
}

// =====================================================================
// prep: block 0 builds dense adjacency (counts + self loops) AND the
// per-target sparse neighbor lists; blocks 1..50 build the pos-emb table.
// =====================================================================
__global__ void prep_kernel(const int* __restrict__ ei, int E0,
                            float* __restrict__ adj, float* __restrict__ pe,
                            int* __restrict__ nbrI, float* __restrict__ nbrW,
                            int* __restrict__ deg) {
    int tid = threadIdx.x;
    if (blockIdx.x == 0) {
        for (int i = tid; i < NTOK * NTOK; i += 64) adj[i] = 0.f;
        __syncthreads();
        bool is64 = (ei[1] == 0);   // int64 little-endian high word
        for (int e = tid; e < E0; e += 64) {
            int s, d;
            if (is64) { s = ei[2 * e]; d = ei[2 * (E0 + e)]; }
            else      { s = ei[e];     d = ei[E0 + e]; }
            if ((unsigned)s < NTOK && (unsigned)d < NTOK)
                atomicAdd(&adj[d * NTOK + s], 1.f);
        }
        if (tid < NTOK) atomicAdd(&adj[tid * NTOK + tid], 1.f);  // self loops
        __syncthreads();
        if (tid > 0 && tid < NTOK) {            // t>=1 sparse in-lists
            int d = 0;
            for (int s = 0; s < NTOK; ++s) {
                float c = adj[tid * NTOK + s];
                if (c > 0.f && d < MAXDEG) { nbrI[tid * MAXDEG + d] = s;
                                             nbrW[tid * MAXDEG + d] = c; ++d; }
            }
            deg[tid] = d;
        }
        if (tid == 0) deg[0] = 0;               // t=0 handled full-width
    } else {
        int t = blockIdx.x - 1;
        for (int j = tid; j < HID; j += 64) {
            float jeff = (float)(j & ~1);
            float ang = (float)t / powf(10000.f, jeff / (float)HID);
            pe[t * HID + j] = ((j & 1) == 0) ? sinf(ang) : cosf(ang);
        }
    }
}

// =====================================================================
// LDS-tiled transpose of all weights to [N][K] canonical bf16.
// =====================================================================
__global__ __launch_bounds__(256) void transpose2(
    const void* __restrict__ Wmap, const void* __restrict__ Wgat,
    const void* __restrict__ W1,   const void* __restrict__ W2,
    const void* __restrict__ Wout, const unsigned short* tag,
    __hip_bfloat16* __restrict__ wmapT, __hip_bfloat16* __restrict__ wgatT,
    __hip_bfloat16* __restrict__ w1T,   __hip_bfloat16* __restrict__ w2T,
    __hip_bfloat16* __restrict__ woutT) {
    __shared__ __hip_bfloat16 tl[64][65];
    bool bf = tag_is_bf16(tag);
    int b = blockIdx.x;
    const void* src; __hip_bfloat16* dst; int R, C, tR; long so, dofs;
    if (b < 192)      { src = Wmap; dst = wmapT; R = 3072; C = 256;  tR = 48;
                        so = 0; dofs = 0; }
    else if (b < 256) { int ti = b - 192, l = ti >> 4; b = ti & 15;
                        src = Wgat; dst = wgatT; R = 256; C = 256; tR = 4;
                        so = (long)l * 65536; dofs = so; goto tiled; }
    else if (b < 512) { int ti = b - 256, l = ti >> 6; b = ti & 63;
                        src = W1; dst = w1T; R = 256; C = 1024; tR = 4;
                        so = (long)l * 262144; dofs = so; goto tiled; }
    else if (b < 768) { int ti = b - 512, l = ti >> 6; b = ti & 63;
                        src = W2; dst = w2T; R = 1024; C = 256; tR = 16;
                        so = (long)l * 262144; dofs = so; goto tiled; }
    else              { b -= 768; src = Wout; dst = woutT; R = 256; C = 1000;
                        tR = 4; so = 0; dofs = 0; }
tiled:
    int r0 = (b % tR) * 64, c0 = (b / tR) * 64;
    int tx = threadIdx.x & 63, ty = threadIdx.x >> 6;
#pragma unroll
    for (int j = 0; j < 16; ++j) {
        int rr = ty + 4 * j;
        float v = (c0 + tx < C) ? ldf(src, so + (long)(r0 + rr) * C + c0 + tx, bf) : 0.f;
        tl[rr][tx] = __float2bfloat16(v);
    }
    __syncthreads();
#pragma unroll
    for (int j = 0; j < 16; ++j) {
        int i2 = ty + 4 * j;
        if (c0 + i2 < C)
            dst[dofs + (long)(c0 + i2) * R + r0 + tx] = tl[tx][i2];
    }
}

// =====================================================================
// init resid with bias + positional emb (+ cls row), float4 stores.
// Runs BEFORE the patch GEMM which accumulates into it (plain +=).
// =====================================================================
__global__ void init_resid(const __hip_bfloat16* __restrict__ sp,
                           const float* __restrict__ pe, float* __restrict__ resid) {
    int idx = blockIdx.x * 256 + threadIdx.x;   // < MROWS*HID/4
    int row = idx >> 6, c4 = (idx & 63) * 4, t = row % NTOK;
    floatx4 o;
#pragma unroll
    for (int i = 0; i < 4; ++i) {
        int c = c4 + i;
        o[i] = (t == 0) ? __bfloat162float(sp[OFF_CLS + c]) + pe[c]
                        : __bfloat162float(sp[OFF_BMAP + c]) + pe[t * HID + c];
    }
    ((floatx4*)resid)[idx] = o;
}

// =====================================================================
// R3: barrier-drain diagnosis. hipcc emits s_waitcnt vmcnt(0) before
// every s_barrier, so in-flight prefetch loads are DRAINED at each
// barrier -> each k-step exposes a full load latency. Fix: fewer
// barriers, more MFMA per barrier.
//
// oneshot64: K=256 GEMM, 64x64 tile, WHOLE K staged in LDS (A+B 67KB,
// +8-short row pad -> frag reads conflict-light). ONE barrier, ONE
// drain per block, then 8 k-frags x 4 MFMA straight.
// MODE 0: outF=acc; 2: outB=bf16(gelu(acc+bias)).
// =====================================================================
#define OPAD 8
template<int MODE>
__global__ __launch_bounds__(256) void oneshot64(
    const __hip_bfloat16* __restrict__ A, const __hip_bfloat16* __restrict__ BT,
    const __hip_bfloat16* __restrict__ bias,
    float* __restrict__ outF, __hip_bfloat16* __restrict__ outB, int N) {
    __shared__ short As[64][256 + OPAD];
    __shared__ short Bs[64][256 + OPAD];
    int tid = threadIdx.x;
    int m0 = blockIdx.x * 64, n0 = blockIdx.y * 64;
    int lr = tid >> 2, cq = (tid & 3) * 64;     // each thread: 64 contig elems
    int lane = tid & 63, wave = tid >> 6;
    int wm = (wave >> 1) * 32, wn = (wave & 1) * 32;
    int q = lane >> 4, r = lane & 15, q8 = q * 8;
    const short* Ag = (const short*)A + (long)(m0 + lr) * 256 + cq;
    const short* Bg = (const short*)BT + (long)(n0 + lr) * 256 + cq;
    int4v a[8], b[8];
#pragma unroll
    for (int u = 0; u < 8; ++u) a[u] = *(const int4v*)(Ag + u * 8);
#pragma unroll
    for (int u = 0; u < 8; ++u) b[u] = *(const int4v*)(Bg + u * 8);
#pragma unroll
    for (int u = 0; u < 8; ++u) *(int4v*)&As[lr][cq + u * 8] = a[u];
#pragma unroll
    for (int u = 0; u < 8; ++u) *(int4v*)&Bs[lr][cq + u * 8] = b[u];
    __syncthreads();
    floatx4 acc[2][2];
#pragma unroll
    for (int i = 0; i < 2; ++i)
#pragma unroll
        for (int j = 0; j < 2; ++j) acc[i][j] = floatx4{0.f, 0.f, 0.f, 0.f};
#pragma unroll
    for (int kk = 0; kk < 8; ++kk) {
        bf16x8 af[2], bfv[2];
#pragma unroll
        for (int i = 0; i < 2; ++i) af[i]  = *(const bf16x8*)&As[wm + 16 * i + r][kk * 32 + q8];
#pragma unroll
        for (int j = 0; j < 2; ++j) bfv[j] = *(const bf16x8*)&Bs[wn + 16 * j + r][kk * 32 + q8];
#pragma unroll
        for (int i = 0; i < 2; ++i)
#pragma unroll
            for (int j = 0; j < 2; ++j)
                acc[i][j] = __builtin_amdgcn_mfma_f32_16x16x32_bf16(af[i], bfv[j], acc[i][j], 0, 0, 0);
    }
    // epilogue: C/D layout col = lane&15, row = quad*4 + reg  [m89-verified]
#pragma unroll
    for (int j = 0; j < 2; ++j) {
        int col = n0 + wn + 16 * j + r;
        float bvv = (MODE != 0) ? __bfloat162float(bias[col]) : 0.f;
#pragma unroll
        for (int i = 0; i < 2; ++i) {
#pragma unroll
            for (int reg = 0; reg < 4; ++reg) {
                int row = m0 + wm + 16 * i + q * 4 + reg;
                float v = acc[i][j][reg];
                long oi = (long)row * N + col;
                if (MODE == 0) outF[oi] = v;
                if (MODE == 2) outB[oi] = __float2bfloat16(fast_gelu(v + bvv));
            }
        }
    }
}

// =====================================================================
// gemm_k1024: C[M,256] += A[M,1024]*BT[256,1024]^T + bias (W2 GEMM).
// 64x64 tile, BK=128 double-buffered -> 8 barriers (was 32), 16 MFMA
// per barrier. outF += acc + bias (residual add fused).
// =====================================================================
#define K2PAD 8
__global__ __launch_bounds__(256) void gemm_k1024(
    const __hip_bfloat16* __restrict__ A, const __hip_bfloat16* __restrict__ BT,
    const __hip_bfloat16* __restrict__ bias, float* __restrict__ outF, int N) {
    __shared__ short As[2][64][128 + K2PAD];
    __shared__ short Bs[2][64][128 + K2PAD];
    int tid = threadIdx.x;
    int m0 = blockIdx.x * 64, n0 = blockIdx.y * 64;
    int lr = tid >> 2, cq = (tid & 3) * 32;     // 32 elems/thread per k-step
    int lane = tid & 63, wave = tid >> 6;
    int wm = (wave >> 1) * 32, wn = (wave & 1) * 32;
    int q = lane >> 4, r = lane & 15, q8 = q * 8;
    const short* Ag = (const short*)A + (long)(m0 + lr) * 1024 + cq;
    const short* Bg = (const short*)BT + (long)(n0 + lr) * 1024 + cq;
    floatx4 acc[2][2];
#pragma unroll
    for (int i = 0; i < 2; ++i)
#pragma unroll
        for (int j = 0; j < 2; ++j) acc[i][j] = floatx4{0.f, 0.f, 0.f, 0.f};
    int4v a0[4], b0[4], a1[4], b1[4];   // two named prefetch slots (rule #20)
#define LD4(slotA, slotB, kt) do { \
    _Pragma("unroll") for (int u = 0; u < 4; ++u) slotA[u] = *(const int4v*)(Ag + (long)(kt) * 128 + u * 8); \
    _Pragma("unroll") for (int u = 0; u < 4; ++u) slotB[u] = *(const int4v*)(Bg + (long)(kt) * 128 + u * 8); } while (0)
#define ST4(buf, slotA, slotB) do { \
    _Pragma("unroll") for (int u = 0; u < 4; ++u) *(int4v*)&As[buf][lr][cq + u * 8] = slotA[u]; \
    _Pragma("unroll") for (int u = 0; u < 4; ++u) *(int4v*)&Bs[buf][lr][cq + u * 8] = slotB[u]; } while (0)
#define MM(buf) do { \
    _Pragma("unroll") for (int kk = 0; kk < 4; ++kk) { \
        bf16x8 af[2], bfv[2]; \
        _Pragma("unroll") for (int i = 0; i < 2; ++i) af[i]  = *(const bf16x8*)&As[buf][wm + 16 * i + r][kk * 32 + q8]; \
        _Pragma("unroll") for (int j = 0; j < 2; ++j) bfv[j] = *(const bf16x8*)&Bs[buf][wn + 16 * j + r][kk * 32 + q8]; \
        _Pragma("unroll") for (int i = 0; i < 2; ++i) \
        _Pragma("unroll") for (int j = 0; j < 2; ++j) \
            acc[i][j] = __builtin_amdgcn_mfma_f32_16x16x32_bf16(af[i], bfv[j], acc[i][j], 0, 0, 0); } } while (0)
    // prologue: slot0 <- kt0, stage buf0; slot1 <- kt1; slot0 <- kt2
    LD4(a0, b0, 0);
    LD4(a1, b1, 1);
    ST4(0, a0, b0);
    LD4(a0, b0, 2);
    __syncthreads();
#pragma unroll
    for (int kt = 0; kt < 8; kt += 2) {
        // phase A: stage kt+1 -> buf1 from slot1, refill slot1 <- kt+3, compute kt
        ST4(1, a1, b1);
        if (kt + 3 < 8) LD4(a1, b1, kt + 3);
        MM(0);
        __syncthreads();
        // phase B: stage kt+2 -> buf0 from slot0, refill slot0 <- kt+4, compute kt+1
        if (kt + 2 < 8) { ST4(0, a0, b0); if (kt + 4 < 8) LD4(a0, b0, kt + 4); }
        MM(1);
        __syncthreads();
    }
#undef LD4
#undef ST4
#undef MM
#pragma unroll
    for (int j = 0; j < 2; ++j) {
        int col = n0 + wn + 16 * j + r;
        float bvv = __bfloat162float(bias[col]);
#pragma unroll
        for (int i = 0; i < 2; ++i)
#pragma unroll
            for (int reg = 0; reg < 4; ++reg) {
                int row = m0 + wm + 16 * i + q * 4 + reg;
                outF[(long)row * N + col] += acc[i][j][reg] + bvv;
            }
    }
}

// =====================================================================
// Head GEMM: logits[256,1000] = resid_cls[256,256] * WoutT^T + bout.
// A-loader reads CLS rows straight from fp32 resid (stride NTOK*HID),
// fusing extract_cls. M=256, K=256 fixed.
// =====================================================================
__global__ __launch_bounds__(256) void head_gemm(
    const float* __restrict__ resid, const __hip_bfloat16* __restrict__ BT,
    const __hip_bfloat16* __restrict__ bias, float* __restrict__ logits, int N) {
    __shared__ short As[64][32];
    __shared__ short Bs[64][32];
    int tid = threadIdx.x;
    int m0 = blockIdx.x * 64, n0 = blockIdx.y * 64;
    int lr = tid >> 2, lc = (tid & 3) * 8;
    int lane = tid & 63, wave = tid >> 6;
    int wm = (wave >> 1) * 32, wn = (wave & 1) * 32;
    int q = lane >> 4, r = lane & 15, q8 = q * 8;
    const short* Bg = (const short*)BT;
    long a0 = (long)(m0 + lr) * (NTOK * HID) + lc;   // CLS row of batch m0+lr
    int bn = n0 + lr;
    long b0 = (long)bn * HID + lc;
    bool v0 = bn < N;
    floatx4 acc[2][2];
#pragma unroll
    for (int i = 0; i < 2; ++i)
#pragma unroll
        for (int j = 0; j < 2; ++j) acc[i][j] = floatx4{0.f, 0.f, 0.f, 0.f};
    int4v za = {0, 0, 0, 0};
    auto loadA = [&](int k0) -> bf16x8 {
        floatx4 f0 = *(const floatx4*)(resid + a0 + k0);
        floatx4 f1 = *(const floatx4*)(resid + a0 + k0 + 4);
        union { bf16x8 v; __hip_bfloat16 h[8]; } u;
#pragma unroll
        for (int i = 0; i < 4; ++i) { u.h[i] = __float2bfloat16(f0[i]);
                                      u.h[4 + i] = __float2bfloat16(f1[i]); }
        return u.v;
    };
    bf16x8 av = loadA(0);
    int4v bv = v0 ? *(const int4v*)(Bg + b0) : za;
    for (int kt = 0; kt < 8; ++kt) {        // K = 256
        __syncthreads();
        *(bf16x8*)&As[lr][lc] = av;
        *(int4v*)&Bs[lr][lc] = bv;
        __syncthreads();
        if (kt < 7) {
            av = loadA((kt + 1) * 32);
            bv = v0 ? *(const int4v*)(Bg + b0 + (kt + 1) * 32) : za;
        }
        bf16x8 af[2], bfv[2];
#pragma unroll
        for (int i = 0; i < 2; ++i) af[i]  = *(const bf16x8*)&As[wm + 16 * i + r][q8];
#pragma unroll
        for (int j = 0; j < 2; ++j) bfv[j] = *(const bf16x8*)&Bs[wn + 16 * j + r][q8];
#pragma unroll
        for (int i = 0; i < 2; ++i)
#pragma unroll
            for (int j = 0; j < 2; ++j)
                acc[i][j] = __builtin_amdgcn_mfma_f32_16x16x32_bf16(af[i], bfv[j], acc[i][j], 0, 0, 0);
    }
#pragma unroll
    for (int j = 0; j < 2; ++j) {
        int col = n0 + wn + 16 * j + r;
        if (col >= N) continue;
        float bvv = __bfloat162float(bias[col]);
#pragma unroll
        for (int i = 0; i < 2; ++i)
#pragma unroll
            for (int reg = 0; reg < 4; ++reg) {
                int row = m0 + wm + 16 * i + q * 4 + reg;
                logits[(long)row * N + col] = acc[i][j][reg] + bvv;
            }
    }
}

// =====================================================================
// Patch-embed GEMM, 64x64 tile, full K=3072, BK=64 (R3: halve barrier
// count vs BK=32 -> 48 drains/block, 8 MFMA per barrier). Keeps R2's
// XCD-grouped bijective swizzle (FETCH 309->89MB) + dbuf + 2 named
// prefetch slots. Patchify fused in the A loader (dtype-branched).
// =====================================================================
#define PPAD 8
__global__ __launch_bounds__(256) void patch_gemm64(
    const void* __restrict__ img, const __hip_bfloat16* __restrict__ wmapT,
    const unsigned short* tag, float* __restrict__ resid) {
    __shared__ short As[2][64][64 + PPAD];
    __shared__ short Bs[2][64][64 + PPAD];
    bool bf = tag_is_bf16(tag);
    int tid = threadIdx.x;
    int L = blockIdx.x;                      // 0..783
    int w = (L & 7) * 98 + (L >> 3);         // XCD x = L%8 owns w in [98x,98x+98)
    int m0 = (w >> 2) * 64, n0 = (w & 3) * 64;
    int lr = tid >> 2, ck0 = (tid & 3) * 16; // 16 k-elems/thread per k-step
    int lane = tid & 63, wave = tid >> 6;
    int wm = (wave >> 1) * 32, wn = (wave & 1) * 32;
    int q = lane >> 4, r = lane & 15, q8 = q * 8;
    int mA = m0 + lr;
    long baseA;
    { int pb = mA / 49, pp = mA % 49; baseA = (long)pb * 150528 + (pp / 7) * 7168 + (pp % 7) * 32; }
    const short* Bg = (const short*)wmapT;
    long b0 = (long)(n0 + lr) * KPATCH;
    floatx4 acc[2][2];
#pragma unroll
    for (int i = 0; i < 2; ++i)
#pragma unroll
        for (int j = 0; j < 2; ++j) acc[i][j] = floatx4{0.f, 0.f, 0.f, 0.f};
    // k -> image offset: k = c*1024 + py*32 + px; chunk of 8 stays in one
    // image row (ck0 multiple of 8). Two chunks per thread: ck0, ck0+8.
    floatx4 fa0_0, fa1_0, fb0_0, fb1_0;      // slot0 fp32 raw (chunks a,b)
    floatx4 fa0_1, fa1_1, fb0_1, fb1_1;      // slot1
    bf16x8  ha_0, hb_0, ha_1, hb_1;          // bf16 raw
    int4v   bva_0, bvb_0, bva_1, bvb_1;      // B slots
    auto loadChunk = [&](int koff, floatx4& f0, floatx4& f1, bf16x8& h) {
        long g = baseA + (koff >> 10) * 50176 + ((koff >> 5) & 31) * 224 + (koff & 31);
        if (bf) { h = *(const bf16x8*)(((const __bf16*)img) + g); }
        else    { const float* f = (const float*)img;
                  f0 = *(const floatx4*)(f + g);
                  f1 = *(const floatx4*)(f + g + 4); }
    };
    auto cvt = [&](const floatx4& f0, const floatx4& f1, const bf16x8& h) -> bf16x8 {
        if (bf) return h;
        union { bf16x8 v; __hip_bfloat16 hh[8]; } u;
#pragma unroll
        for (int j = 0; j < 4; ++j) { u.hh[j]     = __float2bfloat16(f0[j]);
                                      u.hh[4 + j] = __float2bfloat16(f1[j]); }
        return u.v;
    };
#define PLD(s, kt) do { int kb = (kt) * 64 + ck0; \
    loadChunk(kb,     fa0_##s, fa1_##s, ha_##s); \
    loadChunk(kb + 8, fb0_##s, fb1_##s, hb_##s); \
    bva_##s = *(const int4v*)(Bg + b0 + kb); \
    bvb_##s = *(const int4v*)(Bg + b0 + kb + 8); } while (0)
#define PST(buf, s) do { \
    *(bf16x8*)&As[buf][lr][ck0]     = cvt(fa0_##s, fa1_##s, ha_##s); \
    *(bf16x8*)&As[buf][lr][ck0 + 8] = cvt(fb0_##s, fb1_##s, hb_##s); \
    *(int4v*)&Bs[buf][lr][ck0]      = bva_##s; \
    *(int4v*)&Bs[buf][lr][ck0 + 8]  = bvb_##s; } while (0)
#define PMM(buf) do { \
    _Pragma("unroll") for (int kk = 0; kk < 2; ++kk) { \
        bf16x8 af[2], bfv[2]; \
        _Pragma("unroll") for (int i = 0; i < 2; ++i) af[i]  = *(const bf16x8*)&As[buf][wm + 16 * i + r][kk * 32 + q8]; \
        _Pragma("unroll") for (int j = 0; j < 2; ++j) bfv[j] = *(const bf16x8*)&Bs[buf][wn + 16 * j + r][kk * 32 + q8]; \
        _Pragma("unroll") for (int i = 0; i < 2; ++i) \
        _Pragma("unroll") for (int j = 0; j < 2; ++j) \
            acc[i][j] = __builtin_amdgcn_mfma_f32_16x16x32_bf16(af[i], bfv[j], acc[i][j], 0, 0, 0); } } while (0)
    // prologue
    PLD(0, 0);
    PLD(1, 1);
    PST(0, 0);
    PLD(0, 2);
    __syncthreads();
    for (int kt = 0; kt < 48; kt += 2) {
        // phase A: stage kt+1 -> buf1 (slot1), refill slot1 <- kt+3, compute kt
        PST(1, 1);
        if (kt + 3 < 48) PLD(1, kt + 3);
        PMM(0);
        __syncthreads();
        // phase B: stage kt+2 -> buf0 (slot0), refill slot0 <- kt+4, compute kt+1
        if (kt + 2 < 48) { PST(0, 0); if (kt + 4 < 48) PLD(0, kt + 4); }
        PMM(1);
        __syncthreads();
    }
#undef PLD
#undef PST
#undef PMM
    // epilogue: sole owner of each (row,col) -> plain read-modify-write.
    // resid pre-initialized with bias + pos-emb by init_resid.
#pragma unroll
    for (int j = 0; j < 2; ++j) {
        int col = n0 + wn + 16 * j + r;    // always < 256
#pragma unroll
        for (int i = 0; i < 2; ++i) {
#pragma unroll
            for (int reg = 0; reg < 4; ++reg) {
                int row = m0 + wm + 16 * i + q * 4 + reg;
                int bb = row / 49, pp = row % 49;
                long oi = ((long)bb * NTOK + pp + 1) * HID + col;
                resid[oi] += acc[i][j][reg];
            }
        }
    }
}

// =====================================================================
// LayerNorm: one wave per row, float4 loads, fp32 in -> bf16 out
// =====================================================================
__global__ __launch_bounds__(256) void ln_kernel(
    const float* __restrict__ x, const __hip_bfloat16* __restrict__ g,
    const __hip_bfloat16* __restrict__ bta, __hip_bfloat16* __restrict__ y) {
    int row = blockIdx.x * 4 + (threadIdx.x >> 6);
    int lane = threadIdx.x & 63;
    floatx4 v = ((const floatx4*)(x + (long)row * HID))[lane];
    float s = v[0] + v[1] + v[2] + v[3];
#pragma unroll
    for (int off = 32; off; off >>= 1) s += __shfl_xor(s, off, 64);
    float mu = s * (1.f / HID);
    float d2 = 0.f;
#pragma unroll
    for (int i = 0; i < 4; ++i) { float d = v[i] - mu; d2 += d * d; }
#pragma unroll
    for (int off = 32; off; off >>= 1) d2 += __shfl_xor(d2, off, 64);
    float rstd = rsqrtf(d2 * (1.f / HID) + 1e-5f);
    union { short4v s4; __hip_bfloat16 h[4]; } o;
#pragma unroll
    for (int i = 0; i < 4; ++i) {
        int c = lane * 4 + i;
        float t = (v[i] - mu) * rstd * __bfloat162float(g[c]) + __bfloat162float(bta[c]);
        o.h[i] = __float2bfloat16(t);
    }
    ((short4v*)(y + (long)row * HID))[lane] = o.s4;
}

// =====================================================================
// GAT v2: one block per batch. Phase 1: stage h + per-node logits.
// Phase 2: all (t,head) alphas in parallel (sparse lists, t=0 full-width).
// Phase 3: barrier-free sparse aggregation, resid += out + bias.
// =====================================================================
__global__ __launch_bounds__(256) void gat_kernel2(
    const float* __restrict__ h, const float* __restrict__ adj,
    const int* __restrict__ nbrI, const float* __restrict__ nbrW,
    const int* __restrict__ deg,
    const __hip_bfloat16* __restrict__ sp, int l, float* __restrict__ resid) {
    __shared__ float hs[NTOK][HID];                 // 50 KB
    __shared__ float als[NTOK][HEADS], ald[NTOK][HEADS];
    __shared__ float alpha0[HEADS][NTOK];
    __shared__ float alphaC[HEADS][NTOK][MAXDEG];   // 19.2 KB
    __shared__ float attS[HID], attD[HID], bg[HID];
    __shared__ int   nI[NTOK][MAXDEG];
    __shared__ int   dgs[NTOK];
    int b = blockIdx.x, tid = threadIdx.x;
    const float* hb = h + (long)b * (NTOK * HID);
    for (int i = tid; i < NTOK * HID / 4; i += 256)
        ((floatx4*)hs)[i] = ((const floatx4*)hb)[i];
    attS[tid] = __bfloat162float(sp[OFF_ASRC + l * HID + tid]);
    attD[tid] = __bfloat162float(sp[OFF_ADST + l * HID + tid]);
    bg[tid]   = __bfloat162float(sp[OFF_BGAT + l * HID + tid]);
    for (int i = tid; i < NTOK * MAXDEG; i += 256) ((int*)nI)[i] = nbrI[i];
    if (tid < NTOK) dgs[tid] = deg[tid];
    __syncthreads();
    for (int pr = tid; pr < NTOK * HEADS; pr += 256) {   // node logits
        int s = pr >> 3, hh = pr & 7;
        float a1 = 0.f, a2 = 0.f;
#pragma unroll
        for (int d = 0; d < DH; ++d) {
            float hv = hs[s][hh * DH + d];
            a1 += hv * attS[hh * DH + d];
            a2 += hv * attD[hh * DH + d];
        }
        als[s][hh] = a1; ald[s][hh] = a2;
    }
    __syncthreads();
    for (int pr = tid; pr < NTOK * HEADS; pr += 256) {   // edge softmax
        int t = pr >> 3, hh = pr & 7;
        float aldt = ald[t][hh];
        if (t == 0) {
            float mx = -1e30f;
            for (int s = 0; s < NTOK; ++s) {
                float w = adj[s];
                if (w > 0.f) {
                    float e = als[s][hh] + aldt; e = (e > 0.f) ? e : 0.2f * e;
                    mx = fmaxf(mx, e);
                }
            }
            float sum = 0.f;
            for (int s = 0; s < NTOK; ++s) {
                float w = adj[s], v = 0.f;
                if (w > 0.f) {
                    float e = als[s][hh] + aldt; e = (e > 0.f) ? e : 0.2f * e;
                    v = w * expf(e - mx);
                }
                alpha0[hh][s] = v; sum += v;
            }
            float inv = 1.f / (sum + 1e-16f);
            for (int s = 0; s < NTOK; ++s) alpha0[hh][s] *= inv;
        } else {
            int d = dgs[t];
            float mx = -1e30f;
            for (int j = 0; j < d; ++j) {
                float e = als[nI[t][j]][hh] + aldt; e = (e > 0.f) ? e : 0.2f * e;
                mx = fmaxf(mx, e);
            }
            float sum = 0.f;
            for (int j = 0; j < d; ++j) {
                float e = als[nI[t][j]][hh] + aldt; e = (e > 0.f) ? e : 0.2f * e;
                float w = nbrW[t * MAXDEG + j] * expf(e - mx);
                alphaC[hh][t][j] = w; sum += w;
            }
            float inv = 1.f / (sum + 1e-16f);
            for (int j = 0; j < d; ++j) alphaC[hh][t][j] *= inv;
        }
    }
    __syncthreads();
    int hd = tid >> 5, ln32 = tid & 31, col = hd * DH + ln32;
    float* res = resid + (long)b * (NTOK * HID);
    float bgc = bg[col];
    {
        float acc = 0.f;
        for (int s = 0; s < NTOK; ++s) acc += alpha0[hd][s] * hs[s][col];
        res[col] += acc + bgc;
    }
    for (int t = 1; t < NTOK; ++t) {
        float acc = 0.f; int d = dgs[t];
        for (int j = 0; j < d; ++j) acc += alphaC[hd][t][j] * hs[nI[t][j]][col];
        res[t * HID + col] += acc + bgc;
    }
}

// =====================================================================
__global__ __launch_bounds__(256) void softmax_kernel(
    const float* __restrict__ logits, const unsigned short* tag, void* __restrict__ out) {
    __shared__ float red[8];
    bool bf = tag_is_bf16(tag);
    int b = blockIdx.x, tid = threadIdx.x;
    const float* Lr = logits + (long)b * OUTD;
    float v[4], mx = -1e30f;
#pragma unroll
    for (int i = 0; i < 4; ++i) {
        int j = tid + i * 256;
        v[i] = (j < OUTD) ? Lr[j] : -1e30f;
        mx = fmaxf(mx, v[i]);
    }
#pragma unroll
    for (int off = 32; off; off >>= 1) mx = fmaxf(mx, __shfl_xor(mx, off, 64));
    if ((tid & 63) == 0) red[tid >> 6] = mx;
    __syncthreads();
    mx = fmaxf(fmaxf(red[0], red[1]), fmaxf(red[2], red[3]));
    float s = 0.f, ex[4];
#pragma unroll
    for (int i = 0; i < 4; ++i) {
        int j = tid + i * 256;
        ex[i] = (j < OUTD) ? expf(v[i] - mx) : 0.f;
        s += ex[i];
    }
#pragma unroll
    for (int off = 32; off; off >>= 1) s += __shfl_xor(s, off, 64);
    __syncthreads();
    if ((tid & 63) == 0) red[4 + (tid >> 6)] = s;
    __syncthreads();
    float inv = 1.f / (red[4] + red[5] + red[6] + red[7]);
#pragma unroll
    for (int i = 0; i < 4; ++i) {
        int j = tid + i * 256;
        if (j < OUTD) {
            float o = ex[i] * inv;
            if (bf) ((__hip_bfloat16*)out)[(long)b * OUTD + j] = __float2bfloat16(o);
            else    ((float*)out)[(long)b * OUTD + j] = o;
        }
    }
}

// =====================================================================
extern "C" void kernel_launch(void* const* d_in, const int* in_sizes, int n_in,
                              void* d_out, int out_size, void* d_ws, size_t ws_size,
                              hipStream_t stream) {
    const void* images = d_in[0];
    const int*  ei     = (const int*)d_in[1];
    const unsigned short* tag = (const unsigned short*)d_in[9];  // ln1_g (all ones)
    int E0 = in_sizes[1] / 2;

    char* p = (char*)d_ws;
    auto alloc = [&](size_t bytes) { char* r = p; p += (bytes + 255) & ~(size_t)255; return r; };
    float*          resid  = (float*)alloc((size_t)MROWS * HID * 4);
    float*          hbuf   = (float*)alloc((size_t)MROWS * HID * 4);
    __hip_bfloat16* xb     = (__hip_bfloat16*)alloc((size_t)MROWS * HID * 2);
    __hip_bfloat16* mid    = (__hip_bfloat16*)alloc((size_t)MROWS * MLPD * 2);
    float*          logits = (float*)alloc((size_t)BATCH * OUTD * 4);
    float*          pe     = (float*)alloc((size_t)NTOK * HID * 4);
    float*          adj    = (float*)alloc((size_t)NTOK * NTOK * 4);
    int*            nbrI   = (int*)alloc((size_t)NTOK * MAXDEG * 4);
    float*          nbrW   = (float*)alloc((size_t)NTOK * MAXDEG * 4);
    int*            degp   = (int*)alloc((size_t)NTOK * 4);
    __hip_bfloat16* smallp = (__hip_bfloat16*)alloc((size_t)SP_TOTAL * 2);
    __hip_bfloat16* wmapT  = (__hip_bfloat16*)alloc((size_t)KPATCH * HID * 2);
    __hip_bfloat16* wgatT  = (__hip_bfloat16*)alloc((size_t)NBLK * HID * HID * 2);
    __hip_bfloat16* w1T    = (__hip_bfloat16*)alloc((size_t)NBLK * HID * MLPD * 2);
    __hip_bfloat16* w2T    = (__hip_bfloat16*)alloc((size_t)NBLK * HID * MLPD * 2);
    __hip_bfloat16* woutT  = (__hip_bfloat16*)alloc((size_t)HID * OUTD * 2);

    SmallSrc ss = { d_in[3], d_in[4], d_in[6], d_in[7], d_in[8], d_in[9], d_in[10],
                    d_in[11], d_in[12], d_in[14], d_in[16], d_in[18] };
    prep_kernel<<<51, 64, 0, stream>>>(ei, E0, adj, pe, nbrI, nbrW, degp);
    pack_params<<<(SP_TOTAL + 255) / 256, 256, 0, stream>>>(ss, tag, smallp);
    transpose2<<<832, 256, 0, stream>>>(d_in[2], d_in[5], d_in[13], d_in[15],
                                        d_in[17], tag, wmapT, wgatT, w1T, w2T, woutT);
    init_resid<<<MROWS * HID / 1024, 256, 0, stream>>>(smallp, pe, resid);
    patch_gemm64<<<784, 256, 0, stream>>>(images, wmapT, tag, resid);

    for (int l = 0; l < NBLK; ++l) {
        ln_kernel<<<MROWS / 4, 256, 0, stream>>>(resid, smallp + OFF_LN1G + l * HID,
                                                 smallp + OFF_LN1B + l * HID, xb);
        oneshot64<0><<<dim3(MROWS / 64, HID / 64), 256, 0, stream>>>(
            xb, wgatT + l * HID * HID, nullptr, hbuf, nullptr, HID);
        gat_kernel2<<<BATCH, 256, 0, stream>>>(hbuf, adj, nbrI, nbrW, degp,
                                               smallp, l, resid);
        ln_kernel<<<MROWS / 4, 256, 0, stream>>>(resid, smallp + OFF_LN2G + l * HID,
                                                 smallp + OFF_LN2B + l * HID, xb);
        oneshot64<2><<<dim3(MROWS / 64, MLPD / 64), 256, 0, stream>>>(
            xb, w1T + l * HID * MLPD, smallp + OFF_B1 + l * MLPD, nullptr, mid, MLPD);
        gemm_k1024<<<dim3(MROWS / 64, HID / 64), 256, 0, stream>>>(
            mid, w2T + l * HID * MLPD, smallp + OFF_B2 + l * HID, resid, HID);
    }

    head_gemm<<<dim3(BATCH / 64, (OUTD + 63) / 64), 256, 0, stream>>>(
        resid, woutT, smallp + OFF_BOUT, logits, OUTD);
    softmax_kernel<<<BATCH, 256, 0, stream>>>(logits, tag, d_out);
}